// Round 4
// baseline (1177.722 us; speedup 1.0000x reference)
//
#include <hip/hip_runtime.h>
#include <stdint.h>

typedef __attribute__((ext_vector_type(8))) short short8;
typedef __attribute__((ext_vector_type(4))) float floatx4;
typedef __attribute__((ext_vector_type(4))) int int4v;
typedef __attribute__((ext_vector_type(4))) short short4v;

#define NPTS 400000
#define KOFF 27

// fp32 -> bf16 round-to-nearest-even
__device__ __forceinline__ unsigned short f2bf(float v) {
    union { float f; unsigned int u; } a; a.f = v;
    unsigned int r = a.u + 0x7FFFu + ((a.u >> 16) & 1u);
    return (unsigned short)(r >> 16);
}

__global__ __launch_bounds__(256) void cvt_x_kernel(const float* __restrict__ x,
                                                    unsigned short* __restrict__ xb,
                                                    int n4) {
    int t = blockIdx.x * 256 + threadIdx.x;
    if (t >= n4) return;
    floatx4 v = *(const floatx4*)(x + (size_t)t * 4);
    short4v o;
#pragma unroll
    for (int j = 0; j < 4; ++j) o[j] = (short)f2bf(v[j]);
    *(short4v*)(xb + (size_t)t * 4) = o;
}

// pack neighbor idx + mask: bit31 = mask, bits 0..18 = idx (N < 2^19)
__global__ __launch_bounds__(256) void pack_kernel(const int* __restrict__ idx,
                                                   const int* __restrict__ msk,
                                                   int* __restrict__ pk, int n4) {
    int t = blockIdx.x * 256 + threadIdx.x;
    if (t >= n4) return;
    int4v a = *(const int4v*)(idx + (size_t)t * 4);
    int4v m = *(const int4v*)(msk + (size_t)t * 4);
    int4v o;
#pragma unroll
    for (int j = 0; j < 4; ++j) o[j] = a[j] | (m[j] ? (int)0x80000000 : 0);
    *(int4v*)(pk + (size_t)t * 4) = o;
}

// W input: [k][cin][cout] fp32 -> [k][cout][cin] bf16 (B-fragment = contiguous 16B)
__global__ __launch_bounds__(256) void cvt_w_kernel(const float* __restrict__ W,
                                                    unsigned short* __restrict__ wb) {
    int t = blockIdx.x * 256 + threadIdx.x;  // [k][cout][cin]
    int k = t >> 12, cout = (t >> 6) & 63, cin = t & 63;
    wb[t] = f2bf(W[(k << 12) + (cin << 6) + cout]);
}

// One workgroup = 128 points, 4 waves x 32 points. Wave: 2 M-tiles x 4 N-tiles of
// mfma_f32_16x16x32_bf16, contraction over (k=27, cin=64).
//
// Depth-3 gather pipeline. vmcnt retires loads in ISSUE ORDER, so within each
// iteration ALL B-loads are issued BEFORE the gather: waiting for B then leaves
// the 3 outstanding gathers in flight. sched_barrier(0) pins the load cluster
// ahead of the MFMA cluster (the compiler otherwise sinks B-loads into the MFMA
// stream — round-3's 56-VGPR schedule — which drains gathers via the FIFO).
// A-frag: lane(row=lane&15, kg=lane>>4) holds A[row][s*32 + kg*8 + j].
// B-frag: col=lane&15 from wb[k][cout][cin]. D: col=lane&15, row=kg*4+reg (m89).
template <int LAYER>
__global__ __launch_bounds__(256, 3) void conv_layer(
        const unsigned short* __restrict__ xb,
        const unsigned short* __restrict__ wb,
        const float* __restrict__ bias,
        const int* __restrict__ pk,
        const float* __restrict__ xres,
        unsigned short* __restrict__ ob,
        float* __restrict__ outf) {
    const int tid = threadIdx.x;
    const int wv = tid >> 6, lane = tid & 63;
    const int row = lane & 15, kg = lane >> 4;
    const int base = blockIdx.x * 128 + wv * 32;
    const int pr0 = (base + row) * KOFF;
    const int pr1 = (base + 16 + row) * KOFF;
    const int aoff = kg << 3;

    floatx4 acc[2][4];
#pragma unroll
    for (int mt = 0; mt < 2; ++mt)
#pragma unroll
        for (int nt = 0; nt < 4; ++nt) acc[mt][nt] = (floatx4)0.0f;

    short8 A[4][2][2];  // gather ring, statically indexed (full unroll)

#define GATHER(buf, q0, q1) do { \
    (buf)[0][0] = (short8)0; (buf)[0][1] = (short8)0; \
    (buf)[1][0] = (short8)0; (buf)[1][1] = (short8)0; \
    if ((q0) < 0) { \
        const unsigned short* p_ = xb + ((size_t)((q0) & 0x7FFFFFFF) << 6) + aoff; \
        (buf)[0][0] = *(const short8*)p_; (buf)[0][1] = *(const short8*)(p_ + 32); } \
    if ((q1) < 0) { \
        const unsigned short* p_ = xb + ((size_t)((q1) & 0x7FFFFFFF) << 6) + aoff; \
        (buf)[1][0] = *(const short8*)p_; (buf)[1][1] = *(const short8*)(p_ + 32); } \
  } while (0)

    // Prologue: fill ring slots 0..2 (serial, once), start pack pipeline.
    {
        int q0 = pk[pr0 + 0], q1 = pk[pr1 + 0];
        GATHER(A[0], q0, q1);
        q0 = pk[pr0 + 1]; q1 = pk[pr1 + 1];
        GATHER(A[1], q0, q1);
        q0 = pk[pr0 + 2]; q1 = pk[pr1 + 2];
        GATHER(A[2], q0, q1);
    }
    int pgA0 = pk[pr0 + 3], pgA1 = pk[pr1 + 3];   // p(k+3) at k=0
    int pgB0 = pk[pr0 + 4], pgB1 = pk[pr1 + 4];   // p(k+4)
    int pgC0 = pk[pr0 + 5], pgC1 = pk[pr1 + 5];   // p(k+5)

#pragma unroll
    for (int k = 0; k < KOFF; ++k) {
        const unsigned short* wk = wb + (k << 12);
        // --- load cluster: B first (older in vmcnt FIFO), then gather, then pack
        short8 b0[4], b1[4];
#pragma unroll
        for (int nt = 0; nt < 4; ++nt)
            b0[nt] = *(const short8*)(wk + ((nt * 16 + row) << 6) + (kg << 3));
#pragma unroll
        for (int nt = 0; nt < 4; ++nt)
            b1[nt] = *(const short8*)(wk + ((nt * 16 + row) << 6) + 32 + (kg << 3));
        if (k + 3 < KOFF) GATHER(A[(k + 3) & 3], pgA0, pgA1);
        int pl0 = 0, pl1 = 0;
        if (k + 6 < KOFF) { pl0 = pk[pr0 + k + 6]; pl1 = pk[pr1 + k + 6]; }
        __builtin_amdgcn_sched_barrier(0);
        // --- MFMA cluster on ring slot k (gathered 3 iterations ago)
#pragma unroll
        for (int nt = 0; nt < 4; ++nt) {
            acc[0][nt] = __builtin_amdgcn_mfma_f32_16x16x32_bf16(A[k & 3][0][0], b0[nt], acc[0][nt], 0, 0, 0);
            acc[1][nt] = __builtin_amdgcn_mfma_f32_16x16x32_bf16(A[k & 3][1][0], b0[nt], acc[1][nt], 0, 0, 0);
        }
#pragma unroll
        for (int nt = 0; nt < 4; ++nt) {
            acc[0][nt] = __builtin_amdgcn_mfma_f32_16x16x32_bf16(A[k & 3][0][1], b1[nt], acc[0][nt], 0, 0, 0);
            acc[1][nt] = __builtin_amdgcn_mfma_f32_16x16x32_bf16(A[k & 3][1][1], b1[nt], acc[1][nt], 0, 0, 0);
        }
        // rotate pack pipeline (SSA-renamed, no moves)
        pgA0 = pgB0; pgA1 = pgB1;
        pgB0 = pgC0; pgB1 = pgC1;
        pgC0 = pl0;  pgC1 = pl1;
    }
#undef GATHER

    // Epilogue. D layout: col=lane&15, row=kg*4+i.
    const int col = row;
#pragma unroll
    for (int mt = 0; mt < 2; ++mt) {
#pragma unroll
        for (int nt = 0; nt < 4; ++nt) {
            const float bc = bias[nt * 16 + col];
#pragma unroll
            for (int i = 0; i < 4; ++i) {
                const size_t p = base + mt * 16 + kg * 4 + i;
                const int c = nt * 16 + col;
                float v = acc[mt][nt][i] + bc;
                if (LAYER == 0) {
                    ob[p * 64 + c] = f2bf(fmaxf(v, 0.0f));
                } else {
                    outf[p * 64 + c] = v + xres[p * 64 + c];
                }
            }
        }
    }
}

extern "C" void kernel_launch(void* const* d_in, const int* in_sizes, int n_in,
                              void* d_out, int out_size, void* d_ws, size_t ws_size,
                              hipStream_t stream) {
    const float* x  = (const float*)d_in[0];
    const float* W0 = (const float*)d_in[1];
    const float* b0 = (const float*)d_in[2];
    const float* W1 = (const float*)d_in[3];
    const float* b1 = (const float*)d_in[4];
    const int* nidx = (const int*)d_in[5];
    const int* nmask = (const int*)d_in[6];  // jax bool -> harness int32
    float* out = (float*)d_out;

    // Workspace: xb 51.2MB | hb 51.2MB | pk 43.2MB | w0b 221KB | w1b 221KB  (~146MB)
    char* ws = (char*)d_ws;
    const size_t rowBytes = (size_t)NPTS * 64 * sizeof(short);          // 51.2 MB
    const size_t pkBytes  = (size_t)NPTS * KOFF * sizeof(int);          // 43.2 MB
    const size_t wBytes   = (size_t)KOFF * 64 * 64 * sizeof(short);     // 221 KB
    unsigned short* xb = (unsigned short*)(ws);
    unsigned short* hb = (unsigned short*)(ws + rowBytes);
    int* pkbuf         = (int*)(ws + 2 * rowBytes);
    unsigned short* w0b = (unsigned short*)(ws + 2 * rowBytes + pkBytes);
    unsigned short* w1b = (unsigned short*)(ws + 2 * rowBytes + pkBytes + wBytes);

    cvt_x_kernel<<<25000, 256, 0, stream>>>(x, xb, NPTS * 64 / 4);
    pack_kernel<<<10547, 256, 0, stream>>>(nidx, nmask, pkbuf, NPTS * KOFF / 4);
    cvt_w_kernel<<<432, 256, 0, stream>>>(W0, w0b);
    cvt_w_kernel<<<432, 256, 0, stream>>>(W1, w1b);

    conv_layer<0><<<3125, 256, 0, stream>>>(xb, w0b, b0, pkbuf, nullptr, hb, nullptr);
    conv_layer<1><<<3125, 256, 0, stream>>>(hb, w1b, b1, pkbuf, x, nullptr, out);
}